// Round 7
// baseline (293.887 us; speedup 1.0000x reference)
//
#include <hip/hip_runtime.h>

#define NB 4                 // batch
#define GRID_X 640
#define NCELL (GRID_X*GRID_X)      // 409600
#define NWORD (NCELL/32)           // 12800 bitmask words per sample
#define MAXPIL 12000
#define MAXPTS 100
#define WPT (NWORD/256)            // 50 words per thread in the fused scan

typedef unsigned short u16;
typedef unsigned int   u32;

// ---- bf16 round-trip (RTNE) — used ONLY for the pillar-id value write ----
__device__ __forceinline__ float bf16rt(float f) {
    u32 u = __builtin_bit_cast(u32, f);
    u32 r = ((u + 0x7FFFu + ((u >> 16) & 1u)) >> 16) << 16;
    return __builtin_bit_cast(float, r);
}

// value barrier: blocks -ffp-contract=fast from fusing mul into the following sub
__device__ __forceinline__ float opaquef(float x) { asm volatile("" : "+v"(x)); return x; }

// XLA constant-folded reciprocals (verified: round 6 passed bit-exact):
//   1/f32(102.4) == 0.009765625f exactly; 1/f32(0.32f/102.4f) rounds UP to 320+2^-15
#define R102 0.009765625f
#define RWH  320.000030517578125f          // 0x1.400002p8
__device__ __host__ constexpr float WH_N_C() { return (2.0f*0.16f)/(51.2f-(-51.2f)); }

__device__ __forceinline__ float norm_x(float v) {
    float p = 2.0f*(v + 51.2f) * R102;
    return opaquef(p) - 1.0f;
}
__device__ __forceinline__ float norm_z(float v) {
    float p = 2.0f*(v + 5.0f) * 0.125f;
    return opaquef(p) - 1.0f;
}

__device__ __forceinline__ int cell_of(float xn, float yn) {
    float fx = fminf(fmaxf(floorf((xn + 1.0f) * RWH), 0.0f), 639.0f);  // fmax = inert safety clamp
    float fy = fminf(fmaxf(floorf((yn + 1.0f) * RWH), 0.0f), 639.0f);
    return (int)fy * GRID_X + (int)fx;
}

// ---- K0: stream-zero the 173 MB feature region + the small ws zero region ----
__global__ void k_zero(float4* __restrict__ out4, int n4, int4* __restrict__ ws4, int nw4) {
    int i = blockIdx.x*blockDim.x + threadIdx.x;
    if (i < n4) out4[i] = make_float4(0.f,0.f,0.f,0.f);
    if (i < nw4) ws4[i] = make_int4(0,0,0,0);
}

// ---- K1: per-point occupancy bitmask ----
__global__ void k_mask(const float4* __restrict__ pc, int P, u32* __restrict__ occMask) {
    int i = blockIdx.x*blockDim.x + threadIdx.x;
    if (i >= NB*P) return;
    float4 pt = pc[i];
    int cell = cell_of(norm_x(pt.x), norm_x(pt.y));
    int b = i / P;
    atomicOr(&occMask[b*NWORD + (cell >> 5)], 1u << (cell & 31));
}

// ---- K2: fused scan — one 256-thread block per sample, all in LDS ----
// default-fills pillar outputs (-1), popcount-scans the 12800-word bitmask,
// emits wordPrefix + slotCell + bf16 pillar ids.
__global__ __launch_bounds__(256) void k_scan(const u32* __restrict__ occMask,
                                              int* __restrict__ wordPrefix,
                                              float* __restrict__ pillars_f,
                                              int* __restrict__ slotCell) {
    __shared__ int part[256];
    int b = blockIdx.x, t = threadIdx.x;
    // default fill (occupied slots overwritten below, after barrier)
    for (int s = t; s < MAXPIL; s += 256) {
        pillars_f[b*MAXPIL + s] = -1.0f;
        slotCell[b*MAXPIL + s] = -1;
    }
    int base = b*NWORD + t*WPT;
    int sum = 0;
    #pragma unroll 10
    for (int i = 0; i < WPT; i++) sum += __popc(occMask[base + i]);
    part[t] = sum;
    __syncthreads();
    for (int d = 1; d < 256; d <<= 1) {
        int v = (t >= d) ? part[t - d] : 0;
        __syncthreads();
        part[t] += v;
        __syncthreads();
    }
    int prefix = part[t] - sum;         // exclusive prefix for this thread's 50 words
    __syncthreads();                    // order -1 fill stores before occupied overwrites
    for (int i = 0; i < WPT; i++) {
        u32 m = occMask[base + i];
        wordPrefix[b*NWORD + t*WPT + i] = prefix;
        int wbase = (t*WPT + i) << 5;
        while (m) {
            int bit = __ffs(m) - 1;
            m &= m - 1;
            if (prefix < MAXPIL) {
                int cell = wbase + bit;
                slotCell[b*MAXPIL + prefix] = cell;
                pillars_f[b*MAXPIL + prefix] = bf16rt((float)cell);
            }
            prefix++;
        }
    }
}

// ---- K3: scatter point indices into per-pillar arrival lists ----
__global__ void k_scatter(const float4* __restrict__ pc, int P,
                          const u32* __restrict__ occMask, const int* __restrict__ wordPrefix,
                          int* __restrict__ slotCnt, u16* __restrict__ idx16) {
    int i = blockIdx.x*blockDim.x + threadIdx.x;
    if (i >= NB*P) return;
    int b = i / P;
    int p = i - b*P;
    float4 pt = pc[i];
    int cell = cell_of(norm_x(pt.x), norm_x(pt.y));
    int w = cell >> 5, bit = cell & 31;
    u32 m = occMask[b*NWORD + w];
    int slot = wordPrefix[b*NWORD + w] + __popc(m & ((1u << bit) - 1u));
    if (slot >= MAXPIL) return;
    int g = b*MAXPIL + slot;
    int pos = atomicAdd(&slotCnt[g], 1);
    if (pos < MAXPTS) idx16[(size_t)g*MAXPTS + pos] = (u16)p;
}

// ---- K4: one THREAD per pillar: mean, rank, write only the occupied rows ----
__global__ void k_rows(const float4* __restrict__ pc, int P,
                       const int* __restrict__ slotCell, const int* __restrict__ slotCnt,
                       const u16* __restrict__ idx16, float* __restrict__ out) {
    int g = blockIdx.x*blockDim.x + threadIdx.x;   // b*MAXPIL + slot
    if (g >= NB*MAXPIL) return;
    int u = slotCell[g];
    if (u < 0) return;                  // empty pillar: zeros already streamed by k_zero
    int b = g / MAXPIL;
    int ntot = slotCnt[g];
    int n = min(ntot, MAXPTS);          // ~5 points/pillar in this dataset
    const u16* lst = idx16 + (size_t)g*MAXPTS;

    float ax = 0.f, ay = 0.f, az = 0.f;
    for (int j = 0; j < n; j++) {
        float4 pt = pc[b*P + lst[j]];
        ax += norm_x(pt.x); ay += norm_x(pt.y); az += norm_z(pt.z);
    }
    float den = (float)max(ntot, 1);
    float mx = ax/den, my = ay/den, mz = az/den;
    const float wh = WH_N_C();
    float cx = -1.0f + (float)(u % GRID_X)*wh + wh*0.5f;
    float cy = -1.0f + (float)(u / GRID_X)*wh + wh*0.5f;

    float* pil = out + (size_t)g*900;
    for (int j = 0; j < n; j++) {
        int p = lst[j];
        int rk = 0;                     // rank by original point index (stable order)
        for (int k = 0; k < n; k++) rk += (lst[k] < (u16)p) ? 1 : 0;
        float4 pt = pc[b*P + p];
        float xn = norm_x(pt.x), yn = norm_x(pt.y), zn = norm_z(pt.z);
        float* e = pil + rk*9;
        e[0] = xn; e[1] = yn; e[2] = zn; e[3] = pt.w;
        e[4] = fabsf(xn - mx); e[5] = fabsf(yn - my); e[6] = fabsf(zn - mz);
        e[7] = cx - xn; e[8] = cy - yn;
    }
}

extern "C" void kernel_launch(void* const* d_in, const int* in_sizes, int n_in,
                              void* d_out, int out_size, void* d_ws, size_t ws_size,
                              hipStream_t stream) {
    const float4* pc = (const float4*)d_in[0];     // f32 x4 per point
    int P = in_sizes[0] / (NB*4);                  // 50000
    float* out = (float*)d_out;                    // f32 output buffer
    float* pillars_f = out + (size_t)NB*MAXPIL*MAXPTS*9;  // second tuple output (f32)

    // workspace layout (~10.4 MB total, int units) — stay well under ws_size
    u32* occMask   = (u32*)d_ws;                        // NB*NWORD      = 51200  [zeroed]
    int* slotCnt   = (int*)(occMask + NB*NWORD);        // NB*MAXPIL     = 48000  [zeroed]
    int* wordPrefix= slotCnt + NB*MAXPIL;               // NB*NWORD      = 51200
    int* slotCell  = wordPrefix + NB*NWORD;             // NB*MAXPIL     = 48000
    u16* idx16     = (u16*)(slotCell + NB*MAXPIL);      // NB*MAXPIL*MAXPTS u16 = 9.6 MB

    const int nOut4 = NB*MAXPIL*MAXPTS*9/4;             // 10,800,000 float4
    const int nWs4  = (NB*NWORD + NB*MAXPIL)/4;         // 24,800 int4

    k_zero<<<(nOut4+255)/256, 256, 0, stream>>>((float4*)out, nOut4, (int4*)occMask, nWs4);
    k_mask<<<(NB*P+255)/256, 256, 0, stream>>>(pc, P, occMask);
    k_scan<<<NB, 256, 0, stream>>>(occMask, wordPrefix, pillars_f, slotCell);
    k_scatter<<<(NB*P+255)/256, 256, 0, stream>>>(pc, P, occMask, wordPrefix, slotCnt, idx16);
    k_rows<<<(NB*MAXPIL+255)/256, 256, 0, stream>>>(pc, P, slotCell, slotCnt, idx16, out);
}

// Round 8
// 281.125 us; speedup vs baseline: 1.0454x; 1.0454x over previous
//
#include <hip/hip_runtime.h>

#define NB 4                 // batch
#define GRID_X 640
#define NCELL (GRID_X*GRID_X)      // 409600
#define NWORD (NCELL/32)           // 12800 bitmask words per sample
#define MAXPIL 12000
#define MAXPTS 100
#define WPT (NWORD/256)            // 50 words per thread in the fused scan
#define PPB 4                      // pillars per block in k_out (1 wave each)

typedef unsigned short u16;
typedef unsigned int   u32;

// ---- bf16 round-trip (RTNE) — used ONLY for the pillar-id value write ----
__device__ __forceinline__ float bf16rt(float f) {
    u32 u = __builtin_bit_cast(u32, f);
    u32 r = ((u + 0x7FFFu + ((u >> 16) & 1u)) >> 16) << 16;
    return __builtin_bit_cast(float, r);
}

// value barrier: blocks -ffp-contract=fast from fusing mul into the following sub
__device__ __forceinline__ float opaquef(float x) { asm volatile("" : "+v"(x)); return x; }

// XLA constant-folded reciprocals (verified bit-exact in rounds 6/7):
#define R102 0.009765625f
#define RWH  320.000030517578125f          // 0x1.400002p8
__device__ __host__ constexpr float WH_N_C() { return (2.0f*0.16f)/(51.2f-(-51.2f)); }

__device__ __forceinline__ float norm_x(float v) {
    float p = 2.0f*(v + 51.2f) * R102;
    return opaquef(p) - 1.0f;
}
__device__ __forceinline__ float norm_z(float v) {
    float p = 2.0f*(v + 5.0f) * 0.125f;
    return opaquef(p) - 1.0f;
}

__device__ __forceinline__ int cell_of(float xn, float yn) {
    float fx = fminf(fmaxf(floorf((xn + 1.0f) * RWH), 0.0f), 639.0f);
    float fy = fminf(fmaxf(floorf((yn + 1.0f) * RWH), 0.0f), 639.0f);
    return (int)fy * GRID_X + (int)fx;
}

// ---- K0: zero occMask + slotCnt (397 KB) ----
__global__ void k_init(int4* __restrict__ ws4, int nw4) {
    int i = blockIdx.x*blockDim.x + threadIdx.x;
    if (i < nw4) ws4[i] = make_int4(0,0,0,0);
}

// ---- K1: per-point occupancy bitmask ----
__global__ void k_mask(const float4* __restrict__ pc, int P, u32* __restrict__ occMask) {
    int i = blockIdx.x*blockDim.x + threadIdx.x;
    if (i >= NB*P) return;
    float4 pt = pc[i];
    int cell = cell_of(norm_x(pt.x), norm_x(pt.y));
    int b = i / P;
    atomicOr(&occMask[b*NWORD + (cell >> 5)], 1u << (cell & 31));
}

// ---- K2: fused scan — one 256-thread block per sample ----
__global__ __launch_bounds__(256) void k_scan(const u32* __restrict__ occMask,
                                              int* __restrict__ wordPrefix,
                                              float* __restrict__ pillars_f,
                                              int* __restrict__ slotCell) {
    __shared__ int part[256];
    int b = blockIdx.x, t = threadIdx.x;
    for (int s = t; s < MAXPIL; s += 256) {     // default fill; occupied overwritten after barrier
        pillars_f[b*MAXPIL + s] = -1.0f;
        slotCell[b*MAXPIL + s] = -1;
    }
    int base = b*NWORD + t*WPT;
    int sum = 0;
    #pragma unroll 10
    for (int i = 0; i < WPT; i++) sum += __popc(occMask[base + i]);
    part[t] = sum;
    __syncthreads();
    for (int d = 1; d < 256; d <<= 1) {
        int v = (t >= d) ? part[t - d] : 0;
        __syncthreads();
        part[t] += v;
        __syncthreads();
    }
    int prefix = part[t] - sum;                 // exclusive prefix for this thread's words
    __syncthreads();                            // order -1 fills before occupied overwrites
    for (int i = 0; i < WPT; i++) {
        u32 m = occMask[base + i];
        wordPrefix[b*NWORD + t*WPT + i] = prefix;
        int wbase = (t*WPT + i) << 5;
        while (m) {
            int bit = __ffs(m) - 1;
            m &= m - 1;
            if (prefix < MAXPIL) {
                int cell = wbase + bit;
                slotCell[b*MAXPIL + prefix] = cell;
                pillars_f[b*MAXPIL + prefix] = bf16rt((float)cell);
            }
            prefix++;
        }
    }
}

// ---- K3: scatter point indices into per-pillar arrival lists ----
__global__ void k_scatter(const float4* __restrict__ pc, int P,
                          const u32* __restrict__ occMask, const int* __restrict__ wordPrefix,
                          int* __restrict__ slotCnt, u16* __restrict__ idx16) {
    int i = blockIdx.x*blockDim.x + threadIdx.x;
    if (i >= NB*P) return;
    int b = i / P;
    int p = i - b*P;
    float4 pt = pc[i];
    int cell = cell_of(norm_x(pt.x), norm_x(pt.y));
    int w = cell >> 5, bit = cell & 31;
    u32 m = occMask[b*NWORD + w];
    int slot = wordPrefix[b*NWORD + w] + __popc(m & ((1u << bit) - 1u));
    if (slot >= MAXPIL) return;
    int g = b*MAXPIL + slot;
    int pos = atomicAdd(&slotCnt[g], 1);
    if (pos < MAXPTS) idx16[(size_t)g*MAXPTS + pos] = (u16)p;
}

// ---- K4: 4 pillars/block, one wave each: LDS tile, write-once coalesced ----
__global__ __launch_bounds__(256) void k_out(const float4* __restrict__ pc, int P,
                        const int* __restrict__ slotCell, const int* __restrict__ slotCnt,
                        const u16* __restrict__ idx16, float* __restrict__ out) {
    __shared__ __align__(16) float tile[PPB*MAXPTS*9];   // 4 x 3600 B = 14.4 KB
    int wv   = threadIdx.x >> 6;            // wave id in block = local pillar
    int lane = threadIdx.x & 63;
    int g = blockIdx.x*PPB + wv;            // b*MAXPIL + slot
    int b = g / MAXPIL;
    float* mytile = tile + wv*MAXPTS*9;
    float4* t4 = (float4*)mytile;           // 225 float4

    // Phase A: zero own tile region
    for (int i = lane; i < 225; i += 64) t4[i] = make_float4(0.f,0.f,0.f,0.f);

    int u = slotCell[g];
    int ntot = (u >= 0) ? slotCnt[g] : 0;
    int n = min(ntot, MAXPTS);              // ~5 points/pillar in this dataset
    __syncthreads();

    // Phase B: occupied waves scatter rows into LDS by rank
    if (n > 0) {
        const u16* lst = idx16 + (size_t)g*MAXPTS;
        // mean via per-lane partials + wave reduce
        float ax = 0.f, ay = 0.f, az = 0.f;
        for (int j = lane; j < n; j += 64) {
            float4 pt = pc[b*P + lst[j]];
            ax += norm_x(pt.x); ay += norm_x(pt.y); az += norm_z(pt.z);
        }
        for (int msk = 1; msk < 64; msk <<= 1) {
            ax += __shfl_xor(ax, msk);
            ay += __shfl_xor(ay, msk);
            az += __shfl_xor(az, msk);
        }
        float den = (float)max(ntot, 1);
        float mx = ax/den, my = ay/den, mz = az/den;
        const float wh = WH_N_C();
        float cx = -1.0f + (float)(u % GRID_X)*wh + wh*0.5f;
        float cy = -1.0f + (float)(u / GRID_X)*wh + wh*0.5f;

        for (int j = lane; j < n; j += 64) {
            int p = lst[j];
            int rk = 0;                     // rank by original point index (stable order)
            for (int k = 0; k < n; k++) rk += (lst[k] < (u16)p) ? 1 : 0;
            float4 pt = pc[b*P + p];
            float xn = norm_x(pt.x), yn = norm_x(pt.y), zn = norm_z(pt.z);
            float* e = mytile + rk*9;
            e[0] = xn; e[1] = yn; e[2] = zn; e[3] = pt.w;
            e[4] = fabsf(xn - mx); e[5] = fabsf(yn - my); e[6] = fabsf(zn - mz);
            e[7] = cx - xn; e[8] = cy - yn;
        }
    }
    __syncthreads();

    // Phase C: dense coalesced dump — every output byte written exactly once
    float4* out4 = (float4*)out + (size_t)g*225;
    for (int i = lane; i < 225; i += 64) out4[i] = t4[i];
}

extern "C" void kernel_launch(void* const* d_in, const int* in_sizes, int n_in,
                              void* d_out, int out_size, void* d_ws, size_t ws_size,
                              hipStream_t stream) {
    const float4* pc = (const float4*)d_in[0];     // f32 x4 per point
    int P = in_sizes[0] / (NB*4);                  // 50000
    float* out = (float*)d_out;                    // f32 output buffer
    float* pillars_f = out + (size_t)NB*MAXPIL*MAXPTS*9;  // second tuple output (f32)

    // workspace layout (~10.4 MB total, int units)
    u32* occMask   = (u32*)d_ws;                        // NB*NWORD      = 51200  [zeroed]
    int* slotCnt   = (int*)(occMask + NB*NWORD);        // NB*MAXPIL     = 48000  [zeroed]
    int* wordPrefix= slotCnt + NB*MAXPIL;               // NB*NWORD      = 51200
    int* slotCell  = wordPrefix + NB*NWORD;             // NB*MAXPIL     = 48000
    u16* idx16     = (u16*)(slotCell + NB*MAXPIL);      // NB*MAXPIL*MAXPTS u16 = 9.6 MB

    const int nWs4 = (NB*NWORD + NB*MAXPIL)/4;          // 24,800 int4

    k_init<<<(nWs4+255)/256, 256, 0, stream>>>((int4*)occMask, nWs4);
    k_mask<<<(NB*P+255)/256, 256, 0, stream>>>(pc, P, occMask);
    k_scan<<<NB, 256, 0, stream>>>(occMask, wordPrefix, pillars_f, slotCell);
    k_scatter<<<(NB*P+255)/256, 256, 0, stream>>>(pc, P, occMask, wordPrefix, slotCnt, idx16);
    k_out<<<NB*MAXPIL/PPB, 256, 0, stream>>>(pc, P, slotCell, slotCnt, idx16, out);
}

// Round 9
// 243.506 us; speedup vs baseline: 1.2069x; 1.1545x over previous
//
#include <hip/hip_runtime.h>

#define NB 4                 // batch
#define GRID_X 640
#define NCELL (GRID_X*GRID_X)      // 409600
#define NWORD (NCELL/32)           // 12800 bitmask words per sample
#define MAXPIL 12000
#define MAXPTS 100
#define NBLKA (NWORD/256)          // 50 scan blocks per sample

typedef unsigned short u16;
typedef unsigned int   u32;

// ---- bf16 round-trip (RTNE) — used ONLY for the pillar-id value write ----
__device__ __forceinline__ float bf16rt(float f) {
    u32 u = __builtin_bit_cast(u32, f);
    u32 r = ((u + 0x7FFFu + ((u >> 16) & 1u)) >> 16) << 16;
    return __builtin_bit_cast(float, r);
}

// value barrier: blocks -ffp-contract=fast from fusing mul into the following sub
__device__ __forceinline__ float opaquef(float x) { asm volatile("" : "+v"(x)); return x; }

// XLA constant-folded reciprocals (verified bit-exact rounds 6-8):
#define R102 0.009765625f
#define RWH  320.000030517578125f          // 0x1.400002p8
__device__ __host__ constexpr float WH_N_C() { return (2.0f*0.16f)/(51.2f-(-51.2f)); }

__device__ __forceinline__ float norm_x(float v) {
    float p = 2.0f*(v + 51.2f) * R102;
    return opaquef(p) - 1.0f;
}
__device__ __forceinline__ float norm_z(float v) {
    float p = 2.0f*(v + 5.0f) * 0.125f;
    return opaquef(p) - 1.0f;
}

__device__ __forceinline__ int cell_of(float xn, float yn) {
    float fx = fminf(fmaxf(floorf((xn + 1.0f) * RWH), 0.0f), 639.0f);
    float fy = fminf(fmaxf(floorf((yn + 1.0f) * RWH), 0.0f), 639.0f);
    return (int)fy * GRID_X + (int)fx;
}

// ---- K0: zero occMask+slotCnt; prefill pillars=-1.0f, slotCell=-1 ----
__global__ void k_init(int4* __restrict__ ws4, int nw4,
                       float* __restrict__ pillars_f, int* __restrict__ slotCell, int npil) {
    int i = blockIdx.x*blockDim.x + threadIdx.x;
    if (i < nw4) ws4[i] = make_int4(0,0,0,0);
    if (i < npil) { pillars_f[i] = -1.0f; slotCell[i] = -1; }
}

// ---- K1: per-point cell id -> bitmask + pidx cache ----
__global__ void k_mask(const float4* __restrict__ pc, int P,
                       u32* __restrict__ occMask, u32* __restrict__ pidxBuf) {
    int i = blockIdx.x*blockDim.x + threadIdx.x;
    if (i >= NB*P) return;
    float4 pt = pc[i];
    int cell = cell_of(norm_x(pt.x), norm_x(pt.y));
    int b = i / P;
    atomicOr(&occMask[b*NWORD + (cell >> 5)], 1u << (cell & 31));
    pidxBuf[i] = (u32)cell;
}

// ---- K2a: per-256-word popcount block sums (200 blocks) ----
__global__ void k_scanA(const u32* __restrict__ occMask, int* __restrict__ blockSums) {
    __shared__ int lds[256];
    int blk = blockIdx.x % NBLKA;
    int b   = blockIdx.x / NBLKA;
    int w   = blk*256 + threadIdx.x;
    lds[threadIdx.x] = __popc(occMask[b*NWORD + w]);
    __syncthreads();
    for (int d = 128; d > 0; d >>= 1) {
        if (threadIdx.x < d) lds[threadIdx.x] += lds[threadIdx.x + d];
        __syncthreads();
    }
    if (threadIdx.x == 0) blockSums[b*NBLKA + blk] = lds[0];
}

// ---- K2b: word prefixes + emit sorted pillar ids (200 blocks; block offset
//      recomputed redundantly per block via wave shuffle-reduce — no scanB) ----
__global__ __launch_bounds__(256) void k_scanC(const u32* __restrict__ occMask,
                        const int* __restrict__ blockSums,
                        int* __restrict__ wordPrefix, float* __restrict__ pillars_f,
                        int* __restrict__ slotCell) {
    __shared__ int lds[256];
    __shared__ int offs;
    int blk = blockIdx.x % NBLKA;
    int b   = blockIdx.x / NBLKA;
    int tid = threadIdx.x;
    int w   = blk*256 + tid;
    u32 m = occMask[b*NWORD + w];
    int pop = __popc(m);
    lds[tid] = pop;
    if (tid < 64) {                     // NBLKA=50 <= 64: one wave covers all block sums
        int v = (tid < blk) ? blockSums[b*NBLKA + tid] : 0;
        for (int msk = 1; msk < 64; msk <<= 1) v += __shfl_xor(v, msk);
        if (tid == 0) offs = v;
    }
    __syncthreads();
    for (int d = 1; d < 256; d <<= 1) {
        int t = (tid >= d) ? lds[tid - d] : 0;
        __syncthreads();
        lds[tid] += t;
        __syncthreads();
    }
    int prefix = offs + lds[tid] - pop;   // exclusive
    wordPrefix[b*NWORD + w] = prefix;
    int wbase = w << 5;
    while (m) {
        int bit = __ffs(m) - 1;
        m &= m - 1;
        if (prefix < MAXPIL) {
            int cell = wbase + bit;
            slotCell[b*MAXPIL + prefix] = cell;
            pillars_f[b*MAXPIL + prefix] = bf16rt((float)cell);
        }
        prefix++;
    }
}

// ---- K3: scatter point indices into per-pillar arrival lists (pidx cached) ----
__global__ void k_scatter(int P, const u32* __restrict__ pidxBuf,
                          const u32* __restrict__ occMask, const int* __restrict__ wordPrefix,
                          int* __restrict__ slotCnt, u16* __restrict__ idx16) {
    int i = blockIdx.x*blockDim.x + threadIdx.x;
    if (i >= NB*P) return;
    int b = i / P;
    int p = i - b*P;
    int cell = (int)pidxBuf[i];
    int w = cell >> 5, bit = cell & 31;
    u32 m = occMask[b*NWORD + w];
    int slot = wordPrefix[b*NWORD + w] + __popc(m & ((1u << bit) - 1u));
    if (slot >= MAXPIL) return;
    int g = b*MAXPIL + slot;
    int pos = atomicAdd(&slotCnt[g], 1);
    if (pos < MAXPTS) idx16[(size_t)g*MAXPTS + pos] = (u16)p;
}

// ---- K4: one wave per pillar. Ranks are contiguous -> data fills the FIRST
//      n*9 floats; no LDS zero phase. Empty pillars: register zero-stream. ----
__global__ __launch_bounds__(64) void k_write(const float4* __restrict__ pc, int P,
                        const int* __restrict__ slotCell, const int* __restrict__ slotCnt,
                        const u16* __restrict__ idx16, float* __restrict__ out) {
    __shared__ __align__(16) float tile[MAXPTS*9 + 4];
    __shared__ int sIdx[MAXPTS];
    int g = blockIdx.x;                 // b*MAXPIL + slot
    int lane = threadIdx.x;
    float4* out4 = (float4*)out + (size_t)g*225;
    int u = slotCell[g];
    if (u < 0) {                        // empty: no LDS, no barriers
        float4 z = make_float4(0.f,0.f,0.f,0.f);
        for (int i = lane; i < 225; i += 64) out4[i] = z;
        return;
    }
    int b = g / MAXPIL;
    int ntot = slotCnt[g];
    int n = min(ntot, MAXPTS);          // ~5 points/pillar here
    const u16* lst = idx16 + (size_t)g*MAXPTS;

    for (int j = lane; j < n; j += 64) sIdx[j] = lst[j];
    __syncthreads();

    float ax = 0.f, ay = 0.f, az = 0.f;
    for (int j = lane; j < n; j += 64) {
        float4 pt = pc[b*P + sIdx[j]];
        ax += norm_x(pt.x); ay += norm_x(pt.y); az += norm_z(pt.z);
    }
    for (int msk = 1; msk < 64; msk <<= 1) {
        ax += __shfl_xor(ax, msk);
        ay += __shfl_xor(ay, msk);
        az += __shfl_xor(az, msk);
    }
    float den = (float)max(ntot, 1);
    float mx = ax/den, my = ay/den, mz = az/den;
    const float wh = WH_N_C();
    float cx = -1.0f + (float)(u % GRID_X)*wh + wh*0.5f;
    float cy = -1.0f + (float)(u / GRID_X)*wh + wh*0.5f;

    for (int j = lane; j < n; j += 64) {
        int p = sIdx[j];
        int rk = 0;                     // rank by original point index (stable order)
        for (int k = 0; k < n; k++) rk += (sIdx[k] < p) ? 1 : 0;
        float4 pt = pc[b*P + p];
        float xn = norm_x(pt.x), yn = norm_x(pt.y), zn = norm_z(pt.z);
        float* e = tile + rk*9;         // ranks are 0..n-1: contiguous front of tile
        e[0] = xn; e[1] = yn; e[2] = zn; e[3] = pt.w;
        e[4] = fabsf(xn - mx); e[5] = fabsf(yn - my); e[6] = fabsf(zn - mz);
        e[7] = cx - xn; e[8] = cy - yn;
    }
    int nd = n*9;
    int nf4 = (nd + 3) >> 2;
    if (lane < nf4*4 - nd) tile[nd + lane] = 0.f;   // zero the <=3 pad floats
    __syncthreads();

    float4* t4 = (float4*)tile;
    float4 z = make_float4(0.f,0.f,0.f,0.f);
    for (int i = lane; i < 225; i += 64) out4[i] = (i < nf4) ? t4[i] : z;
}

extern "C" void kernel_launch(void* const* d_in, const int* in_sizes, int n_in,
                              void* d_out, int out_size, void* d_ws, size_t ws_size,
                              hipStream_t stream) {
    const float4* pc = (const float4*)d_in[0];     // f32 x4 per point
    int P = in_sizes[0] / (NB*4);                  // 50000
    float* out = (float*)d_out;                    // f32 output buffer
    float* pillars_f = out + (size_t)NB*MAXPIL*MAXPTS*9;  // second tuple output (f32)

    // workspace layout (~11.2 MB total, int units)
    u32* occMask   = (u32*)d_ws;                        // NB*NWORD      = 51200  [zeroed]
    int* slotCnt   = (int*)(occMask + NB*NWORD);        // NB*MAXPIL     = 48000  [zeroed]
    int* wordPrefix= slotCnt + NB*MAXPIL;               // NB*NWORD      = 51200
    int* slotCell  = wordPrefix + NB*NWORD;             // NB*MAXPIL     = 48000
    int* blockSums = slotCell + NB*MAXPIL;              // NB*NBLKA(200) -> pad 256
    u32* pidxBuf   = (u32*)(blockSums + 256);           // NB*P          = 200000
    u16* idx16     = (u16*)(pidxBuf + NB*P);            // NB*MAXPIL*MAXPTS u16 = 9.6 MB

    const int nWs4 = (NB*NWORD + NB*MAXPIL)/4;          // 24,800 int4
    const int npil = NB*MAXPIL;                         // 48,000
    int initThreads = npil > nWs4 ? npil : nWs4;

    k_init<<<(initThreads+255)/256, 256, 0, stream>>>((int4*)occMask, nWs4, pillars_f, slotCell, npil);
    k_mask<<<(NB*P+255)/256, 256, 0, stream>>>(pc, P, occMask, pidxBuf);
    k_scanA<<<NB*NBLKA, 256, 0, stream>>>(occMask, blockSums);
    k_scanC<<<NB*NBLKA, 256, 0, stream>>>(occMask, blockSums, wordPrefix, pillars_f, slotCell);
    k_scatter<<<(NB*P+255)/256, 256, 0, stream>>>(P, pidxBuf, occMask, wordPrefix, slotCnt, idx16);
    k_write<<<NB*MAXPIL, 64, 0, stream>>>(pc, P, slotCell, slotCnt, idx16, out);
}